// Round 1
// baseline (11511.287 us; speedup 1.0000x reference)
//
#include <hip/hip_runtime.h>
#include <math.h>

#define H_COEF 0.1f
#define LN_EPS 1e-5

// ---------------------------------------------------------------------------
// Block-level (sum, sumsq) reduction -> atomicAdd(double) to global stat[2].
// All threads of the block must call this (it has __syncthreads).
// ---------------------------------------------------------------------------
__device__ __forceinline__ void stat_reduce(float s, float ss, double* stat) {
#pragma unroll
  for (int off = 32; off > 0; off >>= 1) {
    s += __shfl_down(s, off);
    ss += __shfl_down(ss, off);
  }
  __shared__ float bs[8], bss[8];
  const int wid = threadIdx.x >> 6;
  const int lane = threadIdx.x & 63;
  if (lane == 0) { bs[wid] = s; bss[wid] = ss; }
  __syncthreads();
  if (threadIdx.x == 0) {
    float S = 0.f, SS = 0.f;
    const int nw = blockDim.x >> 6;
    for (int w = 0; w < nw; w++) { S += bs[w]; SS += bss[w]; }
    atomicAdd(stat, (double)S);
    atomicAdd(stat + 1, (double)SS);
  }
}

// ---------------------------------------------------------------------------
// out(64 x M) = W(64 x KIN) @ xin(KIN x M).  One thread per column.
// ---------------------------------------------------------------------------
template <int KIN>
__global__ void open_kernel(const float* __restrict__ W,
                            const float* __restrict__ xin,
                            float* __restrict__ out, int M) {
  const int e = blockIdx.x * blockDim.x + threadIdx.x;
  if (e >= M) return;
  float x[KIN];
#pragma unroll
  for (int k = 0; k < KIN; k++) x[k] = xin[(size_t)k * M + e];
  for (int c = 0; c < 64; c++) {
    float acc = 0.f;
#pragma unroll
    for (int k = 0; k < KIN; k++) acc += W[c * KIN + k] * x[k];
    out[(size_t)c * M + e] = acc;
  }
}

// In-place close: x(64 x M) <- W(64 x 64) @ x(64 x M).  Column-local, safe.
__global__ void close_inplace_kernel(const float* __restrict__ W,
                                     float* x, int M) {
  const int e = blockIdx.x * blockDim.x + threadIdx.x;
  if (e >= M) return;
  float xv[64];
#pragma unroll 16
  for (int k = 0; k < 64; k++) xv[k] = x[(size_t)k * M + e];
  for (int c = 0; c < 64; c++) {
    float acc = 0.f;
#pragma unroll
    for (int k = 0; k < 64; k++) acc += W[c * 64 + k] * xv[k];
    x[(size_t)c * M + e] = acc;
  }
}

// ---------------------------------------------------------------------------
// U[n][c] = sum_k (0.5*KE1[c][k] + KE1[c][128+k]) * xn[k][n]   (node-major)
// V[n][c] = sum_k (0.5*KE1[c][k] - KE1[c][128+k]) * xn[k][n]
// ---------------------------------------------------------------------------
__global__ void uv_kernel(const float* __restrict__ KE1_l,
                          const float* __restrict__ xn,
                          float* __restrict__ U, float* __restrict__ V, int N) {
  const int n = blockIdx.x * blockDim.x + threadIdx.x;
  if (n >= N) return;
  float x[64];
#pragma unroll 16
  for (int k = 0; k < 64; k++) x[k] = xn[(size_t)k * N + n];
  for (int c = 0; c < 64; c++) {
    const float* row = KE1_l + c * 192;
    float a = 0.f, g = 0.f;
#pragma unroll
    for (int k = 0; k < 64; k++) {
      a += row[k] * x[k];
      g += row[128 + k] * x[k];
    }
    U[(size_t)n * 64 + c] = 0.5f * a + g;
    V[(size_t)n * 64 + c] = 0.5f * a - g;
  }
}

// ---------------------------------------------------------------------------
// edge1: y[:,e] = U[:,i(e)] + V[:,j(e)] + B1 @ xe[:,e];  stats of y.
// B1 = KE1[:, 64:128] (row stride 192).
// ---------------------------------------------------------------------------
__global__ void edge1_kernel(const float* __restrict__ KE1_l,
                             const float* __restrict__ xe,
                             const float* __restrict__ U,
                             const float* __restrict__ V,
                             const int* __restrict__ iInd,
                             const int* __restrict__ jInd,
                             float* __restrict__ y,
                             double* __restrict__ stat, int E) {
  const int e = blockIdx.x * blockDim.x + threadIdx.x;
  float s = 0.f, ss = 0.f;
  if (e < E) {
    const int vi = iInd[e];
    const int vj = jInd[e];
    const float* Up = U + (size_t)vi * 64;
    const float* Vp = V + (size_t)vj * 64;
    float x[64];
#pragma unroll 16
    for (int k = 0; k < 64; k++) x[k] = xe[(size_t)k * E + e];
    for (int c = 0; c < 64; c++) {
      const float* row = KE1_l + c * 192 + 64;
      float acc = Up[c] + Vp[c];
#pragma unroll
      for (int k = 0; k < 64; k++) acc += row[k] * x[k];
      y[(size_t)c * E + e] = acc;
      s += acc;
      ss += acc * acc;
    }
  }
  stat_reduce(s, ss, stat);
}

// ---------------------------------------------------------------------------
// edge2: t = relu(ln(y col)); y col <- KE2 @ t (in place); stats of new y.
// ln params derived from statIn on the fly (uniform scalar work).
// ---------------------------------------------------------------------------
__global__ void edge2_kernel(const float* __restrict__ W,
                             float* y,
                             const double* __restrict__ statIn,
                             double* __restrict__ statOut,
                             double inv_n, int E) {
  const int e = blockIdx.x * blockDim.x + threadIdx.x;
  float s = 0.f, ss = 0.f;
  if (e < E) {
    const double m = statIn[0] * inv_n;
    const double v = statIn[1] * inv_n - m * m;
    const float fm = (float)m;
    const float finv = (float)(1.0 / sqrt(v + LN_EPS));
    float t[64];
#pragma unroll 16
    for (int k = 0; k < 64; k++) {
      float val = (y[(size_t)k * E + e] - fm) * finv;
      t[k] = val > 0.f ? val : 0.f;
    }
    for (int c = 0; c < 64; c++) {
      float acc = 0.f;
#pragma unroll
      for (int k = 0; k < 64; k++) acc += W[c * 64 + k] * t[k];
      y[(size_t)c * E + e] = acc;
      s += acc;
      ss += acc * acc;
    }
  }
  stat_reduce(s, ss, statOut);
}

// ---------------------------------------------------------------------------
// edge3: t = relu(ln(y col)) = xec2;
//   xe col += H * (KE3 @ t)          (in place)
//   atomic scatter: Si[i(e)] += t ; Sj[j(e)] += t   (node-major, 64 floats)
// ---------------------------------------------------------------------------
__global__ void edge3_kernel(const float* __restrict__ W,
                             const float* __restrict__ y,
                             float* xe,
                             const double* __restrict__ statIn,
                             const int* __restrict__ iInd,
                             const int* __restrict__ jInd,
                             float* __restrict__ Si,
                             float* __restrict__ Sj,
                             double inv_n, int E) {
  const int e = blockIdx.x * blockDim.x + threadIdx.x;
  if (e >= E) return;
  const double m = statIn[0] * inv_n;
  const double v = statIn[1] * inv_n - m * m;
  const float fm = (float)m;
  const float finv = (float)(1.0 / sqrt(v + LN_EPS));
  float t[64];
#pragma unroll 16
  for (int k = 0; k < 64; k++) {
    float val = (y[(size_t)k * E + e] - fm) * finv;
    t[k] = val > 0.f ? val : 0.f;
  }
  const int vi = iInd[e];
  const int vj = jInd[e];
  float* sip = Si + (size_t)vi * 64;
  float* sjp = Sj + (size_t)vj * 64;
#pragma unroll 16
  for (int k = 0; k < 64; k++) {
    atomicAdd(sip + k, t[k]);
    atomicAdd(sjp + k, t[k]);
  }
  for (int c = 0; c < 64; c++) {
    float acc = 0.f;
#pragma unroll
    for (int k = 0; k < 64; k++) acc += W[c * 64 + k] * t[k];
    xe[(size_t)c * E + e] += H_COEF * acc;
  }
}

// ---------------------------------------------------------------------------
// node update (in place on xn):
//   xn col += H * ( KN[:,0:64] @ (0.5*(Si+Sj)) + KN[:,64:128] @ xn
//                 + KN[:,128:192] @ (Si - Sj) )
// ---------------------------------------------------------------------------
__global__ void node_update_kernel(const float* __restrict__ KN_l,
                                   float* xn,
                                   const float* __restrict__ Si,
                                   const float* __restrict__ Sj, int N) {
  const int n = blockIdx.x * blockDim.x + threadIdx.x;
  if (n >= N) return;
  float x[64], a[64], d[64];
#pragma unroll 16
  for (int k = 0; k < 64; k++) x[k] = xn[(size_t)k * N + n];
#pragma unroll 16
  for (int k = 0; k < 64; k++) {
    const float si = Si[(size_t)n * 64 + k];
    const float sj = Sj[(size_t)n * 64 + k];
    a[k] = 0.5f * (si + sj);
    d[k] = si - sj;
  }
  for (int c = 0; c < 64; c++) {
    const float* row = KN_l + c * 192;
    float acc = 0.f;
#pragma unroll
    for (int k = 0; k < 64; k++) {
      acc += row[k] * a[k];
      acc += row[64 + k] * x[k];
      acc += row[128 + k] * d[k];
    }
    xn[(size_t)c * N + n] = x[c] + H_COEF * acc;
  }
}

// ---------------------------------------------------------------------------
extern "C" void kernel_launch(void* const* d_in, const int* in_sizes, int n_in,
                              void* d_out, int out_size, void* d_ws,
                              size_t ws_size, hipStream_t stream) {
  const float* xn_in = (const float*)d_in[0];
  const float* xe_in = (const float*)d_in[1];
  const int* iInd = (const int*)d_in[2];
  const int* jInd = (const int*)d_in[3];
  const float* KNopen = (const float*)d_in[4];
  const float* KEopen = (const float*)d_in[5];
  const float* KNclose = (const float*)d_in[6];
  const float* KEclose = (const float*)d_in[7];
  const float* KE1 = (const float*)d_in[8];
  const float* KE2 = (const float*)d_in[9];
  const float* KE3 = (const float*)d_in[10];
  const float* KN = (const float*)d_in[11];

  const int N = in_sizes[0] / 16;  // 20000
  const int E = in_sizes[2];       // 320000
  const int nlayer = in_sizes[8] / (64 * 192);  // 4

  // xn and xe live directly in the output buffer (close is in-place).
  float* out = (float*)d_out;
  float* xn = out;                    // 64*N
  float* xe = out + (size_t)64 * N;   // 64*E

  // Workspace: y (64*E), U, V, Si, Sj (64*N each, Si/Sj contiguous), stats.
  float* ws = (float*)d_ws;
  float* y = ws;
  float* U = y + (size_t)64 * E;
  float* V = U + (size_t)64 * N;
  float* Si = V + (size_t)64 * N;
  float* Sj = Si + (size_t)64 * N;
  double* stat = (double*)(Sj + (size_t)64 * N);  // nlayer * 4 doubles

  const int bn = (N + 255) / 256;
  const int be = (E + 255) / 256;
  const double inv_n = 1.0 / (64.0 * (double)E);

  hipMemsetAsync(stat, 0, (size_t)nlayer * 4 * sizeof(double), stream);

  open_kernel<16><<<bn, 256, 0, stream>>>(KNopen, xn_in, xn, N);
  open_kernel<16><<<be, 256, 0, stream>>>(KEopen, xe_in, xe, E);

  for (int l = 0; l < nlayer; l++) {
    const float* KE1_l = KE1 + (size_t)l * 64 * 192;
    const float* KE2_l = KE2 + (size_t)l * 64 * 64;
    const float* KE3_l = KE3 + (size_t)l * 64 * 64;
    const float* KN_l = KN + (size_t)l * 64 * 192;
    double* st1 = stat + (size_t)l * 4;
    double* st2 = st1 + 2;

    hipMemsetAsync(Si, 0, (size_t)128 * N * sizeof(float), stream);
    uv_kernel<<<bn, 256, 0, stream>>>(KE1_l, xn, U, V, N);
    edge1_kernel<<<be, 256, 0, stream>>>(KE1_l, xe, U, V, iInd, jInd, y, st1, E);
    edge2_kernel<<<be, 256, 0, stream>>>(KE2_l, y, st1, st2, inv_n, E);
    edge3_kernel<<<be, 256, 0, stream>>>(KE3_l, y, xe, st2, iInd, jInd, Si, Sj,
                                         inv_n, E);
    node_update_kernel<<<bn, 256, 0, stream>>>(KN_l, xn, Si, Sj, N);
  }

  close_inplace_kernel<<<bn, 256, 0, stream>>>(KNclose, xn, N);
  close_inplace_kernel<<<be, 256, 0, stream>>>(KEclose, xe, E);
}

// Round 2
// 9575.204 us; speedup vs baseline: 1.2022x; 1.2022x over previous
//
#include <hip/hip_runtime.h>
#include <math.h>

#define H_COEF 0.1f
#define LN_EPS 1e-5

// ---------------------------------------------------------------------------
// Block-level (sum, sumsq) reduction -> atomicAdd(double) to global stat[2].
// ---------------------------------------------------------------------------
__device__ __forceinline__ void stat_reduce(float s, float ss, double* stat) {
#pragma unroll
  for (int off = 32; off > 0; off >>= 1) {
    s += __shfl_down(s, off);
    ss += __shfl_down(ss, off);
  }
  __shared__ float bs[8], bss[8];
  const int wid = threadIdx.x >> 6;
  const int lane = threadIdx.x & 63;
  if (lane == 0) { bs[wid] = s; bss[wid] = ss; }
  __syncthreads();
  if (threadIdx.x == 0) {
    float S = 0.f, SS = 0.f;
    const int nw = blockDim.x >> 6;
    for (int w = 0; w < nw; w++) { S += bs[w]; SS += bss[w]; }
    atomicAdd(stat, (double)S);
    atomicAdd(stat + 1, (double)SS);
  }
}

// ---------------------------------------------------------------------------
// CSR construction (per launch; indices are fixed inputs).
// ---------------------------------------------------------------------------
__global__ void hist_kernel(const int* __restrict__ iInd,
                            const int* __restrict__ jInd,
                            int* __restrict__ cnt_i, int* __restrict__ cnt_j,
                            int E) {
  const int e = blockIdx.x * blockDim.x + threadIdx.x;
  if (e < E) {
    atomicAdd(&cnt_i[iInd[e]], 1);
    atomicAdd(&cnt_j[jInd[e]], 1);
  }
}

// Single-block exclusive scan of cnt -> rowptr[0..N] and cursor copy.
__global__ void scan_kernel(const int* __restrict__ cnt_i,
                            const int* __restrict__ cnt_j,
                            int* __restrict__ rowptr_i, int* __restrict__ cursor_i,
                            int* __restrict__ rowptr_j, int* __restrict__ cursor_j,
                            int N) {
  __shared__ int carry;
  __shared__ int tmp[1024];
  for (int pass = 0; pass < 2; ++pass) {
    const int* cnt = pass ? cnt_j : cnt_i;
    int* rp = pass ? rowptr_j : rowptr_i;
    int* cur = pass ? cursor_j : cursor_i;
    if (threadIdx.x == 0) carry = 0;
    __syncthreads();
    for (int base = 0; base < N; base += 1024) {
      const int idx = base + threadIdx.x;
      const int v = (idx < N) ? cnt[idx] : 0;
      tmp[threadIdx.x] = v;
      int acc = v;
      __syncthreads();
      for (int off = 1; off < 1024; off <<= 1) {
        const int add = (threadIdx.x >= off) ? tmp[threadIdx.x - off] : 0;
        __syncthreads();
        acc += add;
        tmp[threadIdx.x] = acc;
        __syncthreads();
      }
      const int excl = acc - v + carry;
      if (idx < N) { rp[idx] = excl; cur[idx] = excl; }
      __syncthreads();
      if (threadIdx.x == 1023) carry += tmp[1023];
      __syncthreads();
    }
    if (threadIdx.x == 0) rp[N] = carry;
    __syncthreads();
  }
}

__global__ void fill_kernel(const int* __restrict__ iInd,
                            const int* __restrict__ jInd,
                            int* __restrict__ cursor_i, int* __restrict__ cursor_j,
                            int* __restrict__ perm_i, int* __restrict__ perm_j,
                            int E) {
  const int e = blockIdx.x * blockDim.x + threadIdx.x;
  if (e < E) {
    perm_i[atomicAdd(&cursor_i[iInd[e]], 1)] = e;
    perm_j[atomicAdd(&cursor_j[jInd[e]], 1)] = e;
  }
}

// ---------------------------------------------------------------------------
// out(64 x M) = W(64 x KIN) @ xin(KIN x M).  One thread per column.
// ---------------------------------------------------------------------------
template <int KIN>
__global__ void open_kernel(const float* __restrict__ W,
                            const float* __restrict__ xin,
                            float* __restrict__ out, int M) {
  const int e = blockIdx.x * blockDim.x + threadIdx.x;
  if (e >= M) return;
  float x[KIN];
#pragma unroll
  for (int k = 0; k < KIN; k++) x[k] = xin[(size_t)k * M + e];
  for (int c = 0; c < 64; c++) {
    float acc = 0.f;
#pragma unroll
    for (int k = 0; k < KIN; k++) acc += W[c * KIN + k] * x[k];
    out[(size_t)c * M + e] = acc;
  }
}

// In-place close: x(64 x M) <- W(64 x 64) @ x(64 x M).
__global__ void close_inplace_kernel(const float* __restrict__ W,
                                     float* x, int M) {
  const int e = blockIdx.x * blockDim.x + threadIdx.x;
  if (e >= M) return;
  float xv[64];
#pragma unroll 16
  for (int k = 0; k < 64; k++) xv[k] = x[(size_t)k * M + e];
  for (int c = 0; c < 64; c++) {
    float acc = 0.f;
#pragma unroll
    for (int k = 0; k < 64; k++) acc += W[c * 64 + k] * xv[k];
    x[(size_t)c * M + e] = acc;
  }
}

// ---------------------------------------------------------------------------
// U[n][c] = sum_k (0.5*KE1[c][k] + KE1[c][128+k]) * xn[k][n]
// V[n][c] = sum_k (0.5*KE1[c][k] - KE1[c][128+k]) * xn[k][n]
// ---------------------------------------------------------------------------
__global__ void uv_kernel(const float* __restrict__ KE1_l,
                          const float* __restrict__ xn,
                          float* __restrict__ U, float* __restrict__ V, int N) {
  const int n = blockIdx.x * blockDim.x + threadIdx.x;
  if (n >= N) return;
  float x[64];
#pragma unroll 16
  for (int k = 0; k < 64; k++) x[k] = xn[(size_t)k * N + n];
  for (int c = 0; c < 64; c++) {
    const float* row = KE1_l + c * 192;
    float a = 0.f, g = 0.f;
#pragma unroll
    for (int k = 0; k < 64; k++) {
      a += row[k] * x[k];
      g += row[128 + k] * x[k];
    }
    U[(size_t)n * 64 + c] = 0.5f * a + g;
    V[(size_t)n * 64 + c] = 0.5f * a - g;
  }
}

// ---------------------------------------------------------------------------
// edge1: y[e][:] = U[i(e)][:] + V[j(e)][:] + B1 @ xe[:,e];  stats of y.
// y layout: [E][64] (256B contiguous per edge).
// ---------------------------------------------------------------------------
__global__ void edge1_kernel(const float* __restrict__ KE1_l,
                             const float* __restrict__ xe,
                             const float* __restrict__ U,
                             const float* __restrict__ V,
                             const int* __restrict__ iInd,
                             const int* __restrict__ jInd,
                             float* __restrict__ y,
                             double* __restrict__ stat, int E) {
  const int e = blockIdx.x * blockDim.x + threadIdx.x;
  float s = 0.f, ss = 0.f;
  if (e < E) {
    const int vi = iInd[e];
    const int vj = jInd[e];
    const float* Up = U + (size_t)vi * 64;
    const float* Vp = V + (size_t)vj * 64;
    float x[64];
#pragma unroll 16
    for (int k = 0; k < 64; k++) x[k] = xe[(size_t)k * E + e];
    float4* yrow = (float4*)(y + (size_t)e * 64);
    for (int q = 0; q < 16; q++) {
      float4 r;
      float* rp = (float*)&r;
#pragma unroll
      for (int u = 0; u < 4; u++) {
        const int c = q * 4 + u;
        const float* row = KE1_l + c * 192 + 64;
        float acc = Up[c] + Vp[c];
#pragma unroll
        for (int k = 0; k < 64; k++) acc += row[k] * x[k];
        rp[u] = acc;
        s += acc;
        ss += acc * acc;
      }
      yrow[q] = r;
    }
  }
  stat_reduce(s, ss, stat);
}

// ---------------------------------------------------------------------------
// edge2: t = relu(ln(y row)); y row <- KE2 @ t (in place); stats of new y.
// ---------------------------------------------------------------------------
__global__ void edge2_kernel(const float* __restrict__ W,
                             float* y,
                             const double* __restrict__ statIn,
                             double* __restrict__ statOut,
                             double inv_n, int E) {
  const int e = blockIdx.x * blockDim.x + threadIdx.x;
  float s = 0.f, ss = 0.f;
  if (e < E) {
    const double m = statIn[0] * inv_n;
    const double v = statIn[1] * inv_n - m * m;
    const float fm = (float)m;
    const float finv = (float)(1.0 / sqrt(v + LN_EPS));
    float t[64];
    float4* yrow = (float4*)(y + (size_t)e * 64);
#pragma unroll
    for (int q = 0; q < 16; q++) {
      float4 r = yrow[q];
      float* rp = (float*)&r;
#pragma unroll
      for (int u = 0; u < 4; u++) {
        float val = (rp[u] - fm) * finv;
        t[q * 4 + u] = val > 0.f ? val : 0.f;
      }
    }
    for (int q = 0; q < 16; q++) {
      float4 r;
      float* rp = (float*)&r;
#pragma unroll
      for (int u = 0; u < 4; u++) {
        const int c = q * 4 + u;
        float acc = 0.f;
#pragma unroll
        for (int k = 0; k < 64; k++) acc += W[c * 64 + k] * t[k];
        rp[u] = acc;
        s += acc;
        ss += acc * acc;
      }
      yrow[q] = r;
    }
  }
  stat_reduce(s, ss, statOut);
}

// ---------------------------------------------------------------------------
// edge3: t = relu(ln(y row));  xe col += H * (KE3 @ t).  No scatter.
// ---------------------------------------------------------------------------
__global__ void edge3_kernel(const float* __restrict__ W,
                             const float* __restrict__ y,
                             float* xe,
                             const double* __restrict__ statIn,
                             double inv_n, int E) {
  const int e = blockIdx.x * blockDim.x + threadIdx.x;
  if (e >= E) return;
  const double m = statIn[0] * inv_n;
  const double v = statIn[1] * inv_n - m * m;
  const float fm = (float)m;
  const float finv = (float)(1.0 / sqrt(v + LN_EPS));
  float t[64];
  const float4* yrow = (const float4*)(y + (size_t)e * 64);
#pragma unroll
  for (int q = 0; q < 16; q++) {
    float4 r = yrow[q];
    const float* rp = (const float*)&r;
#pragma unroll
    for (int u = 0; u < 4; u++) {
      float val = (rp[u] - fm) * finv;
      t[q * 4 + u] = val > 0.f ? val : 0.f;
    }
  }
  for (int c = 0; c < 64; c++) {
    float acc = 0.f;
#pragma unroll
    for (int k = 0; k < 64; k++) acc += W[c * 64 + k] * t[k];
    xe[(size_t)c * E + e] += H_COEF * acc;
  }
}

// ---------------------------------------------------------------------------
// gather: Si[n][c] = sum over edges e with i(e)=n of relu(ln(y[e][c]));
//         Sj likewise for j.  One 64-lane wave per node.
// ---------------------------------------------------------------------------
__global__ void gather_kernel(const float* __restrict__ y,
                              const int* __restrict__ rowptr_i,
                              const int* __restrict__ perm_i,
                              const int* __restrict__ rowptr_j,
                              const int* __restrict__ perm_j,
                              const double* __restrict__ statIn,
                              double inv_n,
                              float* __restrict__ Si, float* __restrict__ Sj,
                              int N) {
  const int n = blockIdx.x * (blockDim.x >> 6) + (threadIdx.x >> 6);
  const int c = threadIdx.x & 63;
  if (n >= N) return;
  const double m = statIn[0] * inv_n;
  const double v = statIn[1] * inv_n - m * m;
  const float fm = (float)m;
  const float finv = (float)(1.0 / sqrt(v + LN_EPS));

  float acc = 0.f;
  for (int p = rowptr_i[n]; p < rowptr_i[n + 1]; ++p) {
    const float val = (y[(size_t)perm_i[p] * 64 + c] - fm) * finv;
    acc += val > 0.f ? val : 0.f;
  }
  Si[(size_t)n * 64 + c] = acc;

  acc = 0.f;
  for (int p = rowptr_j[n]; p < rowptr_j[n + 1]; ++p) {
    const float val = (y[(size_t)perm_j[p] * 64 + c] - fm) * finv;
    acc += val > 0.f ? val : 0.f;
  }
  Sj[(size_t)n * 64 + c] = acc;
}

// ---------------------------------------------------------------------------
// node update (in place on xn):
//   xn col += H * ( KN[:,0:64] @ (0.5*(Si+Sj)) + KN[:,64:128] @ xn
//                 + KN[:,128:192] @ (Si - Sj) )
// ---------------------------------------------------------------------------
__global__ void node_update_kernel(const float* __restrict__ KN_l,
                                   float* xn,
                                   const float* __restrict__ Si,
                                   const float* __restrict__ Sj, int N) {
  const int n = blockIdx.x * blockDim.x + threadIdx.x;
  if (n >= N) return;
  float x[64], a[64], d[64];
#pragma unroll 16
  for (int k = 0; k < 64; k++) x[k] = xn[(size_t)k * N + n];
#pragma unroll 16
  for (int k = 0; k < 64; k++) {
    const float si = Si[(size_t)n * 64 + k];
    const float sj = Sj[(size_t)n * 64 + k];
    a[k] = 0.5f * (si + sj);
    d[k] = si - sj;
  }
  for (int c = 0; c < 64; c++) {
    const float* row = KN_l + c * 192;
    float acc = 0.f;
#pragma unroll
    for (int k = 0; k < 64; k++) {
      acc += row[k] * a[k];
      acc += row[64 + k] * x[k];
      acc += row[128 + k] * d[k];
    }
    xn[(size_t)c * N + n] = x[c] + H_COEF * acc;
  }
}

// ---------------------------------------------------------------------------
extern "C" void kernel_launch(void* const* d_in, const int* in_sizes, int n_in,
                              void* d_out, int out_size, void* d_ws,
                              size_t ws_size, hipStream_t stream) {
  const float* xn_in = (const float*)d_in[0];
  const float* xe_in = (const float*)d_in[1];
  const int* iInd = (const int*)d_in[2];
  const int* jInd = (const int*)d_in[3];
  const float* KNopen = (const float*)d_in[4];
  const float* KEopen = (const float*)d_in[5];
  const float* KNclose = (const float*)d_in[6];
  const float* KEclose = (const float*)d_in[7];
  const float* KE1 = (const float*)d_in[8];
  const float* KE2 = (const float*)d_in[9];
  const float* KE3 = (const float*)d_in[10];
  const float* KN = (const float*)d_in[11];

  const int N = in_sizes[0] / 16;               // 20000
  const int E = in_sizes[2];                    // 320000
  const int nlayer = in_sizes[8] / (64 * 192);  // 4

  // xn and xe live directly in the output buffer (close is in-place).
  float* out = (float*)d_out;
  float* xn = out;                   // 64*N
  float* xe = out + (size_t)64 * N;  // 64*E

  // Workspace layout.
  float* ws = (float*)d_ws;
  float* y = ws;                      // 64*E   ([E][64] layout)
  float* U = y + (size_t)64 * E;      // 64*N   (node-major)
  float* V = U + (size_t)64 * N;
  float* Si = V + (size_t)64 * N;
  float* Sj = Si + (size_t)64 * N;
  double* stat = (double*)(Sj + (size_t)64 * N);  // nlayer*4 doubles
  int* cnt_i = (int*)(stat + 4 * nlayer);
  int* cnt_j = cnt_i + N;
  int* rowptr_i = cnt_j + N;
  int* cursor_i = rowptr_i + (N + 1);
  int* rowptr_j = cursor_i + N;
  int* cursor_j = rowptr_j + (N + 1);
  int* perm_i = cursor_j + N;
  int* perm_j = perm_i + E;

  const int bn = (N + 255) / 256;
  const int be = (E + 255) / 256;
  const int bg = (N + 3) / 4;  // gather: 4 nodes per 256-thread block
  const double inv_n = 1.0 / (64.0 * (double)E);

  hipMemsetAsync(stat, 0, (size_t)nlayer * 4 * sizeof(double), stream);
  hipMemsetAsync(cnt_i, 0, (size_t)2 * N * sizeof(int), stream);

  // CSR build (once per launch; indices are fixed inputs).
  hist_kernel<<<be, 256, 0, stream>>>(iInd, jInd, cnt_i, cnt_j, E);
  scan_kernel<<<1, 1024, 0, stream>>>(cnt_i, cnt_j, rowptr_i, cursor_i,
                                      rowptr_j, cursor_j, N);
  fill_kernel<<<be, 256, 0, stream>>>(iInd, jInd, cursor_i, cursor_j,
                                      perm_i, perm_j, E);

  open_kernel<16><<<bn, 256, 0, stream>>>(KNopen, xn_in, xn, N);
  open_kernel<16><<<be, 256, 0, stream>>>(KEopen, xe_in, xe, E);

  for (int l = 0; l < nlayer; l++) {
    const float* KE1_l = KE1 + (size_t)l * 64 * 192;
    const float* KE2_l = KE2 + (size_t)l * 64 * 64;
    const float* KE3_l = KE3 + (size_t)l * 64 * 64;
    const float* KN_l = KN + (size_t)l * 64 * 192;
    double* st1 = stat + (size_t)l * 4;
    double* st2 = st1 + 2;

    uv_kernel<<<bn, 256, 0, stream>>>(KE1_l, xn, U, V, N);
    edge1_kernel<<<be, 256, 0, stream>>>(KE1_l, xe, U, V, iInd, jInd, y, st1, E);
    edge2_kernel<<<be, 256, 0, stream>>>(KE2_l, y, st1, st2, inv_n, E);
    edge3_kernel<<<be, 256, 0, stream>>>(KE3_l, y, xe, st2, inv_n, E);
    gather_kernel<<<bg, 256, 0, stream>>>(y, rowptr_i, perm_i, rowptr_j, perm_j,
                                          st2, inv_n, Si, Sj, N);
    node_update_kernel<<<bn, 256, 0, stream>>>(KN_l, xn, Si, Sj, N);
  }

  close_inplace_kernel<<<bn, 256, 0, stream>>>(KNclose, xn, N);
  close_inplace_kernel<<<be, 256, 0, stream>>>(KEclose, xe, E);
}

// Round 3
// 3362.899 us; speedup vs baseline: 3.4230x; 2.8473x over previous
//
#include <hip/hip_runtime.h>
#include <math.h>

#define H_COEF 0.1f
#define LN_EPS 1e-5

// ---------------------------------------------------------------------------
// Block-level (sum, sumsq) reduction -> atomicAdd(double) to global stat[2].
// ---------------------------------------------------------------------------
__device__ __forceinline__ void stat_reduce(float s, float ss, double* stat) {
#pragma unroll
  for (int off = 32; off > 0; off >>= 1) {
    s += __shfl_down(s, off);
    ss += __shfl_down(ss, off);
  }
  __shared__ float bs[8], bss[8];
  const int wid = threadIdx.x >> 6;
  const int lane = threadIdx.x & 63;
  if (lane == 0) { bs[wid] = s; bss[wid] = ss; }
  __syncthreads();
  if (threadIdx.x == 0) {
    float S = 0.f, SS = 0.f;
    const int nw = blockDim.x >> 6;
    for (int w = 0; w < nw; w++) { S += bs[w]; SS += bss[w]; }
    atomicAdd(stat, (double)S);
    atomicAdd(stat + 1, (double)SS);
  }
}

// ---------------------------------------------------------------------------
// CSR construction (per launch; indices are fixed inputs).
// ---------------------------------------------------------------------------
__global__ __launch_bounds__(256) void hist_kernel(
    const int* __restrict__ iInd, const int* __restrict__ jInd,
    int* __restrict__ cnt_i, int* __restrict__ cnt_j, int E) {
  const int e = blockIdx.x * blockDim.x + threadIdx.x;
  if (e < E) {
    atomicAdd(&cnt_i[iInd[e]], 1);
    atomicAdd(&cnt_j[jInd[e]], 1);
  }
}

// Single-block exclusive scan of cnt -> rowptr[0..N] and cursor copy.
__global__ __launch_bounds__(1024) void scan_kernel(
    const int* __restrict__ cnt_i, const int* __restrict__ cnt_j,
    int* __restrict__ rowptr_i, int* __restrict__ cursor_i,
    int* __restrict__ rowptr_j, int* __restrict__ cursor_j, int N) {
  __shared__ int carry;
  __shared__ int tmp[1024];
  for (int pass = 0; pass < 2; ++pass) {
    const int* cnt = pass ? cnt_j : cnt_i;
    int* rp = pass ? rowptr_j : rowptr_i;
    int* cur = pass ? cursor_j : cursor_i;
    if (threadIdx.x == 0) carry = 0;
    __syncthreads();
    for (int base = 0; base < N; base += 1024) {
      const int idx = base + threadIdx.x;
      const int v = (idx < N) ? cnt[idx] : 0;
      tmp[threadIdx.x] = v;
      int acc = v;
      __syncthreads();
      for (int off = 1; off < 1024; off <<= 1) {
        const int add = (threadIdx.x >= off) ? tmp[threadIdx.x - off] : 0;
        __syncthreads();
        acc += add;
        tmp[threadIdx.x] = acc;
        __syncthreads();
      }
      const int excl = acc - v + carry;
      if (idx < N) { rp[idx] = excl; cur[idx] = excl; }
      __syncthreads();
      if (threadIdx.x == 1023) carry += tmp[1023];
      __syncthreads();
    }
    if (threadIdx.x == 0) rp[N] = carry;
    __syncthreads();
  }
}

__global__ __launch_bounds__(256) void fill_kernel(
    const int* __restrict__ iInd, const int* __restrict__ jInd,
    int* __restrict__ cursor_i, int* __restrict__ cursor_j,
    int* __restrict__ perm_i, int* __restrict__ perm_j, int E) {
  const int e = blockIdx.x * blockDim.x + threadIdx.x;
  if (e < E) {
    perm_i[atomicAdd(&cursor_i[iInd[e]], 1)] = e;
    perm_j[atomicAdd(&cursor_j[jInd[e]], 1)] = e;
  }
}

// ---------------------------------------------------------------------------
// out(64 x M) = W(64 x KIN) @ xin(KIN x M).  One thread per column.
// ---------------------------------------------------------------------------
template <int KIN>
__global__ __launch_bounds__(256) void open_kernel(
    const float* __restrict__ W, const float* __restrict__ xin,
    float* __restrict__ out, int M) {
  const int e = blockIdx.x * blockDim.x + threadIdx.x;
  if (e >= M) return;
  float x[KIN];
#pragma unroll
  for (int k = 0; k < KIN; k++) x[k] = xin[(size_t)k * M + e];
#pragma unroll
  for (int c = 0; c < 64; c++) {
    float acc = 0.f;
#pragma unroll
    for (int k = 0; k < KIN; k++) acc += W[c * KIN + k] * x[k];
    out[(size_t)c * M + e] = acc;
  }
}

// In-place close: x(64 x M) <- W(64 x 64) @ x(64 x M).
__global__ __launch_bounds__(256) void close_inplace_kernel(
    const float* __restrict__ W, float* x, int M) {
  const int e = blockIdx.x * blockDim.x + threadIdx.x;
  if (e >= M) return;
  float xv[64];
#pragma unroll
  for (int k = 0; k < 64; k++) xv[k] = x[(size_t)k * M + e];
#pragma unroll
  for (int c = 0; c < 64; c++) {
    float acc = 0.f;
#pragma unroll
    for (int k = 0; k < 64; k++) acc += W[c * 64 + k] * xv[k];
    x[(size_t)c * M + e] = acc;
  }
}

// ---------------------------------------------------------------------------
// U[n][c] = sum_k (0.5*KE1[c][k] + KE1[c][128+k]) * xn[k][n]
// V[n][c] = sum_k (0.5*KE1[c][k] - KE1[c][128+k]) * xn[k][n]
// ---------------------------------------------------------------------------
__global__ __launch_bounds__(256) void uv_kernel(
    const float* __restrict__ KE1_l, const float* __restrict__ xn,
    float* __restrict__ U, float* __restrict__ V, int N) {
  const int n = blockIdx.x * blockDim.x + threadIdx.x;
  if (n >= N) return;
  float x[64];
#pragma unroll
  for (int k = 0; k < 64; k++) x[k] = xn[(size_t)k * N + n];
#pragma unroll
  for (int c = 0; c < 64; c++) {
    const float* row = KE1_l + c * 192;
    float a = 0.f, g = 0.f;
#pragma unroll
    for (int k = 0; k < 64; k++) {
      a += row[k] * x[k];
      g += row[128 + k] * x[k];
    }
    U[(size_t)n * 64 + c] = 0.5f * a + g;
    V[(size_t)n * 64 + c] = 0.5f * a - g;
  }
}

// ---------------------------------------------------------------------------
// edge1: y[e][:] = U[i(e)][:] + V[j(e)][:] + B1 @ xe[:,e];  stats of y.
// y layout: [E][64].
// ---------------------------------------------------------------------------
__global__ __launch_bounds__(256) void edge1_kernel(
    const float* __restrict__ KE1_l, const float* __restrict__ xe,
    const float* __restrict__ U, const float* __restrict__ V,
    const int* __restrict__ iInd, const int* __restrict__ jInd,
    float* __restrict__ y, double* __restrict__ stat, int E) {
  const int e = blockIdx.x * blockDim.x + threadIdx.x;
  float s = 0.f, ss = 0.f;
  if (e < E) {
    const int vi = iInd[e];
    const int vj = jInd[e];
    const float4* Up = (const float4*)(U + (size_t)vi * 64);
    const float4* Vp = (const float4*)(V + (size_t)vj * 64);
    float x[64];
#pragma unroll
    for (int k = 0; k < 64; k++) x[k] = xe[(size_t)k * E + e];
    float4* yrow = (float4*)(y + (size_t)e * 64);
#pragma unroll
    for (int q = 0; q < 16; q++) {
      float4 uq = Up[q];
      float4 vq = Vp[q];
      float4 r;
      float* rp = (float*)&r;
      const float* up = (const float*)&uq;
      const float* vp = (const float*)&vq;
#pragma unroll
      for (int u = 0; u < 4; u++) {
        const int c = q * 4 + u;
        const float* row = KE1_l + c * 192 + 64;
        float acc = up[u] + vp[u];
#pragma unroll
        for (int k = 0; k < 64; k++) acc += row[k] * x[k];
        rp[u] = acc;
        s += acc;
        ss += acc * acc;
      }
      yrow[q] = r;
    }
  }
  stat_reduce(s, ss, stat);
}

// ---------------------------------------------------------------------------
// edge2: t = relu(ln(y row)); y row <- KE2 @ t (in place); stats of new y.
// ---------------------------------------------------------------------------
__global__ __launch_bounds__(256) void edge2_kernel(
    const float* __restrict__ W, float* y, const double* __restrict__ statIn,
    double* __restrict__ statOut, double inv_n, int E) {
  const int e = blockIdx.x * blockDim.x + threadIdx.x;
  float s = 0.f, ss = 0.f;
  if (e < E) {
    const double m = statIn[0] * inv_n;
    const double v = statIn[1] * inv_n - m * m;
    const float fm = (float)m;
    const float finv = (float)(1.0 / sqrt(v + LN_EPS));
    float t[64];
    float4* yrow = (float4*)(y + (size_t)e * 64);
#pragma unroll
    for (int q = 0; q < 16; q++) {
      float4 r = yrow[q];
      const float* rp = (const float*)&r;
#pragma unroll
      for (int u = 0; u < 4; u++) {
        float val = (rp[u] - fm) * finv;
        t[q * 4 + u] = val > 0.f ? val : 0.f;
      }
    }
#pragma unroll
    for (int q = 0; q < 16; q++) {
      float4 r;
      float* rp = (float*)&r;
#pragma unroll
      for (int u = 0; u < 4; u++) {
        const int c = q * 4 + u;
        float acc = 0.f;
#pragma unroll
        for (int k = 0; k < 64; k++) acc += W[c * 64 + k] * t[k];
        rp[u] = acc;
        s += acc;
        ss += acc * acc;
      }
      yrow[q] = r;
    }
  }
  stat_reduce(s, ss, statOut);
}

// ---------------------------------------------------------------------------
// edge3: t = relu(ln(y row));  xe col += H * (KE3 @ t).  No scatter.
// ---------------------------------------------------------------------------
__global__ __launch_bounds__(256) void edge3_kernel(
    const float* __restrict__ W, const float* __restrict__ y, float* xe,
    const double* __restrict__ statIn, double inv_n, int E) {
  const int e = blockIdx.x * blockDim.x + threadIdx.x;
  if (e >= E) return;
  const double m = statIn[0] * inv_n;
  const double v = statIn[1] * inv_n - m * m;
  const float fm = (float)m;
  const float finv = (float)(1.0 / sqrt(v + LN_EPS));
  float t[64];
  const float4* yrow = (const float4*)(y + (size_t)e * 64);
#pragma unroll
  for (int q = 0; q < 16; q++) {
    float4 r = yrow[q];
    const float* rp = (const float*)&r;
#pragma unroll
    for (int u = 0; u < 4; u++) {
      float val = (rp[u] - fm) * finv;
      t[q * 4 + u] = val > 0.f ? val : 0.f;
    }
  }
#pragma unroll
  for (int c = 0; c < 64; c++) {
    float acc = 0.f;
#pragma unroll
    for (int k = 0; k < 64; k++) acc += W[c * 64 + k] * t[k];
    xe[(size_t)c * E + e] += H_COEF * acc;
  }
}

// ---------------------------------------------------------------------------
// gather: Si[n][c] = sum over edges e with i(e)=n of relu(ln(y[e][c]));
//         Sj likewise for j.  One 64-lane wave per node.
// ---------------------------------------------------------------------------
__global__ __launch_bounds__(256) void gather_kernel(
    const float* __restrict__ y, const int* __restrict__ rowptr_i,
    const int* __restrict__ perm_i, const int* __restrict__ rowptr_j,
    const int* __restrict__ perm_j, const double* __restrict__ statIn,
    double inv_n, float* __restrict__ Si, float* __restrict__ Sj, int N) {
  const int n = blockIdx.x * (blockDim.x >> 6) + (threadIdx.x >> 6);
  const int c = threadIdx.x & 63;
  if (n >= N) return;
  const double m = statIn[0] * inv_n;
  const double v = statIn[1] * inv_n - m * m;
  const float fm = (float)m;
  const float finv = (float)(1.0 / sqrt(v + LN_EPS));

  float acc = 0.f;
  for (int p = rowptr_i[n]; p < rowptr_i[n + 1]; ++p) {
    const float val = (y[(size_t)perm_i[p] * 64 + c] - fm) * finv;
    acc += val > 0.f ? val : 0.f;
  }
  Si[(size_t)n * 64 + c] = acc;

  acc = 0.f;
  for (int p = rowptr_j[n]; p < rowptr_j[n + 1]; ++p) {
    const float val = (y[(size_t)perm_j[p] * 64 + c] - fm) * finv;
    acc += val > 0.f ? val : 0.f;
  }
  Sj[(size_t)n * 64 + c] = acc;
}

// ---------------------------------------------------------------------------
// node update, split in two to stay within 256 VGPRs.
//   A: tmp[c][n] = KN[:,0:64] @ (0.5*(Si+Sj)) + KN[:,128:192] @ (Si - Sj)
//   B: xn[c][n] = xn[c][n] + H * ( tmp[c][n] + KN[:,64:128] @ xn col )
// tmp is feature-major [64][N]; all global accesses coalesced.
// ---------------------------------------------------------------------------
__global__ __launch_bounds__(256) void node_a_kernel(
    const float* __restrict__ KN_l, const float* __restrict__ Si,
    const float* __restrict__ Sj, float* __restrict__ tmp, int N) {
  const int n = blockIdx.x * blockDim.x + threadIdx.x;
  if (n >= N) return;
  float a[64], d[64];
#pragma unroll
  for (int k = 0; k < 64; k++) {
    const float si = Si[(size_t)n * 64 + k];
    const float sj = Sj[(size_t)n * 64 + k];
    a[k] = 0.5f * (si + sj);
    d[k] = si - sj;
  }
#pragma unroll
  for (int c = 0; c < 64; c++) {
    const float* row = KN_l + c * 192;
    float acc = 0.f;
#pragma unroll
    for (int k = 0; k < 64; k++) {
      acc += row[k] * a[k];
      acc += row[128 + k] * d[k];
    }
    tmp[(size_t)c * N + n] = acc;
  }
}

__global__ __launch_bounds__(256) void node_b_kernel(
    const float* __restrict__ KN_l, float* xn, const float* __restrict__ tmp,
    int N) {
  const int n = blockIdx.x * blockDim.x + threadIdx.x;
  if (n >= N) return;
  float x[64];
#pragma unroll
  for (int k = 0; k < 64; k++) x[k] = xn[(size_t)k * N + n];
#pragma unroll
  for (int c = 0; c < 64; c++) {
    const float* row = KN_l + c * 192 + 64;
    float acc = tmp[(size_t)c * N + n];
#pragma unroll
    for (int k = 0; k < 64; k++) acc += row[k] * x[k];
    xn[(size_t)c * N + n] = x[c] + H_COEF * acc;
  }
}

// ---------------------------------------------------------------------------
extern "C" void kernel_launch(void* const* d_in, const int* in_sizes, int n_in,
                              void* d_out, int out_size, void* d_ws,
                              size_t ws_size, hipStream_t stream) {
  const float* xn_in = (const float*)d_in[0];
  const float* xe_in = (const float*)d_in[1];
  const int* iInd = (const int*)d_in[2];
  const int* jInd = (const int*)d_in[3];
  const float* KNopen = (const float*)d_in[4];
  const float* KEopen = (const float*)d_in[5];
  const float* KNclose = (const float*)d_in[6];
  const float* KEclose = (const float*)d_in[7];
  const float* KE1 = (const float*)d_in[8];
  const float* KE2 = (const float*)d_in[9];
  const float* KE3 = (const float*)d_in[10];
  const float* KN = (const float*)d_in[11];

  const int N = in_sizes[0] / 16;               // 20000
  const int E = in_sizes[2];                    // 320000
  const int nlayer = in_sizes[8] / (64 * 192);  // 4

  // xn and xe live directly in the output buffer (close is in-place).
  float* out = (float*)d_out;
  float* xn = out;                   // 64*N
  float* xe = out + (size_t)64 * N;  // 64*E

  // Workspace layout.
  float* ws = (float*)d_ws;
  float* y = ws;                  // 64*E   ([E][64] layout)
  float* U = y + (size_t)64 * E;  // 64*N   (node-major [N][64])
  float* V = U + (size_t)64 * N;
  float* Si = V + (size_t)64 * N;
  float* Sj = Si + (size_t)64 * N;
  float* tmp = Sj + (size_t)64 * N;  // 64*N  (feature-major [64][N])
  double* stat = (double*)(tmp + (size_t)64 * N);  // nlayer*4 doubles
  int* cnt_i = (int*)(stat + 4 * nlayer);
  int* cnt_j = cnt_i + N;
  int* rowptr_i = cnt_j + N;
  int* cursor_i = rowptr_i + (N + 1);
  int* rowptr_j = cursor_i + N;
  int* cursor_j = rowptr_j + (N + 1);
  int* perm_i = cursor_j + N;
  int* perm_j = perm_i + E;

  const int bn = (N + 255) / 256;
  const int be = (E + 255) / 256;
  const int bg = (N + 3) / 4;  // gather: 4 waves of 64 per block
  const double inv_n = 1.0 / (64.0 * (double)E);

  hipMemsetAsync(stat, 0, (size_t)nlayer * 4 * sizeof(double), stream);
  hipMemsetAsync(cnt_i, 0, (size_t)2 * N * sizeof(int), stream);

  // CSR build (once per launch; indices are fixed inputs).
  hist_kernel<<<be, 256, 0, stream>>>(iInd, jInd, cnt_i, cnt_j, E);
  scan_kernel<<<1, 1024, 0, stream>>>(cnt_i, cnt_j, rowptr_i, cursor_i,
                                      rowptr_j, cursor_j, N);
  fill_kernel<<<be, 256, 0, stream>>>(iInd, jInd, cursor_i, cursor_j, perm_i,
                                      perm_j, E);

  open_kernel<16><<<bn, 256, 0, stream>>>(KNopen, xn_in, xn, N);
  open_kernel<16><<<be, 256, 0, stream>>>(KEopen, xe_in, xe, E);

  for (int l = 0; l < nlayer; l++) {
    const float* KE1_l = KE1 + (size_t)l * 64 * 192;
    const float* KE2_l = KE2 + (size_t)l * 64 * 64;
    const float* KE3_l = KE3 + (size_t)l * 64 * 64;
    const float* KN_l = KN + (size_t)l * 64 * 192;
    double* st1 = stat + (size_t)l * 4;
    double* st2 = st1 + 2;

    uv_kernel<<<bn, 256, 0, stream>>>(KE1_l, xn, U, V, N);
    edge1_kernel<<<be, 256, 0, stream>>>(KE1_l, xe, U, V, iInd, jInd, y, st1,
                                         E);
    edge2_kernel<<<be, 256, 0, stream>>>(KE2_l, y, st1, st2, inv_n, E);
    edge3_kernel<<<be, 256, 0, stream>>>(KE3_l, y, xe, st2, inv_n, E);
    gather_kernel<<<bg, 256, 0, stream>>>(y, rowptr_i, perm_i, rowptr_j,
                                          perm_j, st2, inv_n, Si, Sj, N);
    node_a_kernel<<<bn, 256, 0, stream>>>(KN_l, Si, Sj, tmp, N);
    node_b_kernel<<<bn, 256, 0, stream>>>(KN_l, xn, tmp, N);
  }

  close_inplace_kernel<<<bn, 256, 0, stream>>>(KNclose, xn, N);
  close_inplace_kernel<<<be, 256, 0, stream>>>(KEclose, xe, E);
}